// Round 2
// baseline (758.453 us; speedup 1.0000x reference)
//
#include <hip/hip_runtime.h>

static constexpr int NUM_GRAPHS = 64;
static constexpr int DH = 64;      // hidden dim == wave size
static constexpr int DOUT = 7;

// ---------- CSR build ----------
__global__ void count_kernel(const int* __restrict__ ei, int* __restrict__ deg, int E) {
    int e = blockIdx.x * blockDim.x + threadIdx.x;
    if (e < E) atomicAdd(&deg[ei[E + e]], 1);   // dst row of edge_index
}

__global__ __launch_bounds__(1024) void scan_kernel(const int* __restrict__ deg,
                                                    int* __restrict__ rowptr,
                                                    int* __restrict__ cursor,
                                                    float* __restrict__ dinv, int N) {
    __shared__ int part[1024];
    int t = threadIdx.x;
    int per = (N + 1023) / 1024;
    int s = t * per, e = min(N, s + per);
    int sum = 0;
    for (int i = s; i < e; ++i) sum += deg[i];
    part[t] = sum;
    __syncthreads();
    for (int off = 1; off < 1024; off <<= 1) {
        int v = (t >= off) ? part[t - off] : 0;
        __syncthreads();
        part[t] += v;
        __syncthreads();
    }
    int run = (t == 0) ? 0 : part[t - 1];
    for (int i = s; i < e; ++i) {
        int d = deg[i];
        rowptr[i] = run;
        cursor[i] = run;
        dinv[i] = rsqrtf((float)(d + 1));   // +1: self-loop, deg always > 0
        run += d;
    }
    if (t == 1023) rowptr[N] = run;
}

__global__ void fill_kernel(const int* __restrict__ ei, int* __restrict__ cursor,
                            const float* __restrict__ dinv, int2* __restrict__ csr, int E) {
    int e = blockIdx.x * blockDim.x + threadIdx.x;
    if (e >= E) return;
    int src = ei[e];
    int dst = ei[E + e];
    int pos = atomicAdd(&cursor[dst], 1);
    float w = dinv[src] * dinv[dst];
    csr[pos] = make_int2(src, __float_as_int(w));
}

// ---------- dense GEMM: h[N,64] = x[N,K] @ W[K,64]; lane = output column ----------
template <int K>
__global__ __launch_bounds__(256) void gemm_kernel(const float* __restrict__ x,
                                                   const float* __restrict__ W,
                                                   float* __restrict__ h, int N) {
    int lane = threadIdx.x & 63;
    int wavesPerBlock = blockDim.x >> 6;
    int wid = blockIdx.x * wavesPerBlock + (threadIdx.x >> 6);
    int nWaves = gridDim.x * wavesPerBlock;

    float wcol[K];
#pragma unroll
    for (int k = 0; k < K; ++k) wcol[k] = W[k * DH + lane];  // coalesced across lanes

    int rowsPer = (N + nWaves - 1) / nWaves;
    int r0 = wid * rowsPer;
    int r1 = min(N, r0 + rowsPer);
    for (int r = r0; r < r1; ++r) {
        const float4* xr = (const float4*)(x + (size_t)r * K);
        float acc = 0.f;
#pragma unroll
        for (int k4 = 0; k4 < K / 4; ++k4) {
            float4 xv = xr[k4];           // uniform address -> broadcast, 1 line
            acc = fmaf(xv.x, wcol[4 * k4 + 0], acc);
            acc = fmaf(xv.y, wcol[4 * k4 + 1], acc);
            acc = fmaf(xv.z, wcol[4 * k4 + 2], acc);
            acc = fmaf(xv.w, wcol[4 * k4 + 3], acc);
        }
        h[(size_t)r * DH + lane] = acc;
    }
}

// ---------- sparse aggregation: one wave per node, lane = channel ----------
__global__ __launch_bounds__(256) void agg_kernel(const float* __restrict__ h,
                                                  const int2* __restrict__ csr,
                                                  const int* __restrict__ rowptr,
                                                  const float* __restrict__ dinv,
                                                  const float* __restrict__ bias,
                                                  float* __restrict__ out, int N) {
    int lane = threadIdx.x & 63;
    int node = blockIdx.x * (blockDim.x >> 6) + (threadIdx.x >> 6);
    if (node >= N) return;
    float di = dinv[node];
    float acc = di * di * h[(size_t)node * DH + lane];   // self-loop term
    int beg = rowptr[node], end = rowptr[node + 1];
    for (int i = beg; i < end; ++i) {
        int2 e = csr[i];                                  // uniform 8B load
        float w = __int_as_float(e.y);
        acc = fmaf(w, h[(size_t)e.x * DH + lane], acc);   // coalesced 256B gather
    }
    out[(size_t)node * DH + lane] = fmaxf(acc + bias[lane], 0.f);
}

// ---------- mean pool over sorted batch (JK-cat of x1,x2) ----------
__global__ __launch_bounds__(128) void pool_kernel(const float* __restrict__ x1,
                                                   const float* __restrict__ x2,
                                                   const int* __restrict__ batch,
                                                   float* __restrict__ pool,
                                                   float* __restrict__ cntf,
                                                   int N, int nodesPerBlock) {
    int f = threadIdx.x;  // 0..127
    int start = blockIdx.x * nodesPerBlock;
    int end = min(N, start + nodesPerBlock);
    if (start >= end) return;
    int gcur = batch[start];
    float acc = 0.f;
    int c = 0;
    for (int v = start; v < end; ++v) {
        int g = batch[v];               // uniform across block
        if (g != gcur) {
            atomicAdd(&pool[gcur * 128 + f], acc);
            if (f == 0) atomicAdd(&cntf[gcur], (float)c);
            acc = 0.f; c = 0; gcur = g;
        }
        acc += (f < DH) ? x1[(size_t)v * DH + f] : x2[(size_t)v * DH + (f - DH)];
        ++c;
    }
    atomicAdd(&pool[gcur * 128 + f], acc);
    if (f == 0) atomicAdd(&cntf[gcur], (float)c);
}

// ---------- head: (pool/cnt) @ Wlin + blin ----------
__global__ __launch_bounds__(512) void final_kernel(const float* __restrict__ pool,
                                                    const float* __restrict__ cntf,
                                                    const float* __restrict__ Wlin,
                                                    const float* __restrict__ blin,
                                                    float* __restrict__ out) {
    int t = threadIdx.x;
    if (t >= NUM_GRAPHS * DOUT) return;
    int g = t / DOUT, o = t % DOUT;
    float inv = 1.0f / fmaxf(cntf[g], 1.0f);
    float acc = 0.f;
    for (int k = 0; k < 2 * DH; ++k)
        acc = fmaf(pool[g * 128 + k], Wlin[k * DOUT + o], acc);
    out[t] = acc * inv + blin[o];
}

extern "C" void kernel_launch(void* const* d_in, const int* in_sizes, int n_in,
                              void* d_out, int out_size, void* d_ws, size_t ws_size,
                              hipStream_t stream) {
    const float* x    = (const float*)d_in[0];
    const int*   ei   = (const int*)d_in[1];
    const int*   batch= (const int*)d_in[2];
    const float* W1   = (const float*)d_in[3];
    const float* b1   = (const float*)d_in[4];
    const float* W2   = (const float*)d_in[5];
    const float* b2   = (const float*)d_in[6];
    const float* Wlin = (const float*)d_in[7];
    const float* blin = (const float*)d_in[8];
    float* out = (float*)d_out;

    const int N = in_sizes[2];          // 50000
    const int E = in_sizes[1] / 2;      // 800000
    const int DIN = in_sizes[0] / N;    // 128

    // workspace carve-up (256B aligned)
    char* base = (char*)d_ws;
    size_t off = 0;
    auto alloc = [&](size_t bytes) {
        char* p = base + off;
        off = (off + bytes + 255) & ~(size_t)255;
        return p;
    };
    int*   deg    = (int*)  alloc((size_t)N * 4);
    int*   rowptr = (int*)  alloc((size_t)(N + 1) * 4);
    int*   cursor = (int*)  alloc((size_t)N * 4);
    float* dinv   = (float*)alloc((size_t)N * 4);
    int2*  csr    = (int2*) alloc((size_t)E * 8);
    float* h      = (float*)alloc((size_t)N * DH * 4);   // reused for layer-2 pre-agg
    float* x1     = (float*)alloc((size_t)N * DH * 4);
    float* x2     = (float*)alloc((size_t)N * DH * 4);
    float* pool   = (float*)alloc((size_t)NUM_GRAPHS * 128 * 4);
    float* cntf   = (float*)alloc((size_t)NUM_GRAPHS * 4);
    (void)ws_size; (void)n_in; (void)out_size; (void)DIN;

    // zero the accumulators (ws is poisoned 0xAA before every call)
    hipMemsetAsync(deg, 0, (size_t)N * 4, stream);
    hipMemsetAsync(pool, 0, (size_t)NUM_GRAPHS * 128 * 4, stream);
    hipMemsetAsync(cntf, 0, (size_t)NUM_GRAPHS * 4, stream);

    // CSR build (shared by both conv layers)
    count_kernel<<<(E + 255) / 256, 256, 0, stream>>>(ei, deg, E);
    scan_kernel<<<1, 1024, 0, stream>>>(deg, rowptr, cursor, dinv, N);
    fill_kernel<<<(E + 255) / 256, 256, 0, stream>>>(ei, cursor, dinv, csr, E);

    // layer 1
    gemm_kernel<128><<<512, 256, 0, stream>>>(x, W1, h, N);
    agg_kernel<<<(N + 3) / 4, 256, 0, stream>>>(h, csr, rowptr, dinv, b1, x1, N);
    // layer 2 (h buffer reused)
    gemm_kernel<64><<<512, 256, 0, stream>>>(x1, W2, h, N);
    agg_kernel<<<(N + 3) / 4, 256, 0, stream>>>(h, csr, rowptr, dinv, b2, x2, N);

    // pooling + head
    const int nodesPerBlock = 512;
    pool_kernel<<<(N + nodesPerBlock - 1) / nodesPerBlock, 128, 0, stream>>>(
        x1, x2, batch, pool, cntf, N, nodesPerBlock);
    final_kernel<<<1, 512, 0, stream>>>(pool, cntf, Wlin, blin, out);
}

// Round 3
// 501.961 us; speedup vs baseline: 1.5110x; 1.5110x over previous
//
#include <hip/hip_runtime.h>

static constexpr int NUM_GRAPHS = 64;
static constexpr int DH = 64;      // hidden dim == wave size
static constexpr int DOUT = 7;

// ---------- CSR build ----------
__global__ void count_kernel(const int* __restrict__ ei, int* __restrict__ deg, int E) {
    int e = blockIdx.x * blockDim.x + threadIdx.x;
    if (e < E) atomicAdd(&deg[ei[E + e]], 1);   // dst row of edge_index
}

__global__ __launch_bounds__(1024) void scan_kernel(const int* __restrict__ deg,
                                                    int* __restrict__ rowptr,
                                                    int* __restrict__ cursor,
                                                    float* __restrict__ dinv, int N) {
    __shared__ int part[1024];
    int t = threadIdx.x;
    int per = (N + 1023) / 1024;
    int s = t * per, e = min(N, s + per);
    int sum = 0;
    for (int i = s; i < e; ++i) sum += deg[i];
    part[t] = sum;
    __syncthreads();
    for (int off = 1; off < 1024; off <<= 1) {
        int v = (t >= off) ? part[t - off] : 0;
        __syncthreads();
        part[t] += v;
        __syncthreads();
    }
    int run = (t == 0) ? 0 : part[t - 1];
    for (int i = s; i < e; ++i) {
        int d = deg[i];
        rowptr[i] = run;
        cursor[i] = run;
        dinv[i] = rsqrtf((float)(d + 1));   // +1: self-loop
        run += d;
    }
    if (t == 1023) rowptr[N] = run;
}

__global__ void fill_kernel(const int* __restrict__ ei, int* __restrict__ cursor,
                            const float* __restrict__ dinv, int2* __restrict__ csr, int E) {
    int e = blockIdx.x * blockDim.x + threadIdx.x;
    if (e >= E) return;
    int src = ei[e];
    int dst = ei[E + e];
    int pos = atomicAdd(&cursor[dst], 1);
    float w = dinv[src] * dinv[dst];
    csr[pos] = make_int2(src, __float_as_int(w));
}

// ---------- dense GEMM: h[N,64] = x[N,K] @ W[K,64] ----------
// wave = 4 rows, lane = output column. W stays in L1 (32 KB), loads coalesced
// across lanes and amortized over 4 rows; 16 independent FMA chains.
template <int K>
__global__ __launch_bounds__(256) void gemm_kernel(const float* __restrict__ x,
                                                   const float* __restrict__ W,
                                                   float* __restrict__ h, int N) {
    int c = threadIdx.x & 63;
    int w = blockIdx.x * (blockDim.x >> 6) + (threadIdx.x >> 6);
    int r0 = w * 4;
    if (r0 >= N) return;

    if (r0 + 4 <= N) {
        float acc[4][4] = {};
#pragma unroll 4
        for (int k4 = 0; k4 < K / 4; ++k4) {
            float w0 = W[(4 * k4 + 0) * DH + c];
            float w1 = W[(4 * k4 + 1) * DH + c];
            float w2 = W[(4 * k4 + 2) * DH + c];
            float w3 = W[(4 * k4 + 3) * DH + c];
#pragma unroll
            for (int i = 0; i < 4; ++i) {
                float4 xv = *(const float4*)(x + (size_t)(r0 + i) * K + 4 * k4);
                acc[i][0] = fmaf(xv.x, w0, acc[i][0]);
                acc[i][1] = fmaf(xv.y, w1, acc[i][1]);
                acc[i][2] = fmaf(xv.z, w2, acc[i][2]);
                acc[i][3] = fmaf(xv.w, w3, acc[i][3]);
            }
        }
#pragma unroll
        for (int i = 0; i < 4; ++i)
            h[(size_t)(r0 + i) * DH + c] =
                (acc[i][0] + acc[i][1]) + (acc[i][2] + acc[i][3]);
    } else {
        for (int r = r0; r < N; ++r) {
            float a0 = 0.f, a1 = 0.f, a2 = 0.f, a3 = 0.f;
            for (int k4 = 0; k4 < K / 4; ++k4) {
                float4 xv = *(const float4*)(x + (size_t)r * K + 4 * k4);
                a0 = fmaf(xv.x, W[(4 * k4 + 0) * DH + c], a0);
                a1 = fmaf(xv.y, W[(4 * k4 + 1) * DH + c], a1);
                a2 = fmaf(xv.z, W[(4 * k4 + 2) * DH + c], a2);
                a3 = fmaf(xv.w, W[(4 * k4 + 3) * DH + c], a3);
            }
            h[(size_t)r * DH + c] = (a0 + a1) + (a2 + a3);
        }
    }
}

// ---------- sparse aggregation: one wave per node, lane = channel ----------
// edge loop unrolled x4: 4 independent csr loads + 4 independent row gathers
// in flight per wave -> hides L2/LLC latency.
__global__ __launch_bounds__(256) void agg_kernel(const float* __restrict__ h,
                                                  const int2* __restrict__ csr,
                                                  const int* __restrict__ rowptr,
                                                  const float* __restrict__ dinv,
                                                  const float* __restrict__ bias,
                                                  float* __restrict__ out, int N) {
    int lane = threadIdx.x & 63;
    int node = blockIdx.x * (blockDim.x >> 6) + (threadIdx.x >> 6);
    if (node >= N) return;
    float di = dinv[node];
    float a0 = di * di * h[(size_t)node * DH + lane];   // self-loop term
    float a1 = 0.f, a2 = 0.f, a3 = 0.f;
    int beg = rowptr[node], end = rowptr[node + 1];
    int i = beg;
    for (; i + 4 <= end; i += 4) {
        int2 e0 = csr[i + 0];
        int2 e1 = csr[i + 1];
        int2 e2 = csr[i + 2];
        int2 e3 = csr[i + 3];
        a0 = fmaf(__int_as_float(e0.y), h[(size_t)e0.x * DH + lane], a0);
        a1 = fmaf(__int_as_float(e1.y), h[(size_t)e1.x * DH + lane], a1);
        a2 = fmaf(__int_as_float(e2.y), h[(size_t)e2.x * DH + lane], a2);
        a3 = fmaf(__int_as_float(e3.y), h[(size_t)e3.x * DH + lane], a3);
    }
    for (; i < end; ++i) {
        int2 e = csr[i];
        a0 = fmaf(__int_as_float(e.y), h[(size_t)e.x * DH + lane], a0);
    }
    float acc = (a0 + a1) + (a2 + a3);
    out[(size_t)node * DH + lane] = fmaxf(acc + bias[lane], 0.f);
}

// ---------- mean pool over sorted batch (JK-cat of x1,x2) ----------
__global__ __launch_bounds__(128) void pool_kernel(const float* __restrict__ x1,
                                                   const float* __restrict__ x2,
                                                   const int* __restrict__ batch,
                                                   float* __restrict__ pool,
                                                   float* __restrict__ cntf,
                                                   int N, int nodesPerBlock) {
    int f = threadIdx.x;  // 0..127
    int start = blockIdx.x * nodesPerBlock;
    int end = min(N, start + nodesPerBlock);
    if (start >= end) return;
    int gcur = batch[start];
    float acc = 0.f;
    int c = 0;
    for (int v = start; v < end; ++v) {
        int g = batch[v];               // uniform across block
        if (g != gcur) {
            atomicAdd(&pool[gcur * 128 + f], acc);
            if (f == 0) atomicAdd(&cntf[gcur], (float)c);
            acc = 0.f; c = 0; gcur = g;
        }
        acc += (f < DH) ? x1[(size_t)v * DH + f] : x2[(size_t)v * DH + (f - DH)];
        ++c;
    }
    atomicAdd(&pool[gcur * 128 + f], acc);
    if (f == 0) atomicAdd(&cntf[gcur], (float)c);
}

// ---------- head: (pool/cnt) @ Wlin + blin ----------
__global__ __launch_bounds__(512) void final_kernel(const float* __restrict__ pool,
                                                    const float* __restrict__ cntf,
                                                    const float* __restrict__ Wlin,
                                                    const float* __restrict__ blin,
                                                    float* __restrict__ out) {
    int t = threadIdx.x;
    if (t >= NUM_GRAPHS * DOUT) return;
    int g = t / DOUT, o = t % DOUT;
    float inv = 1.0f / fmaxf(cntf[g], 1.0f);
    float acc = 0.f;
    for (int k = 0; k < 2 * DH; ++k)
        acc = fmaf(pool[g * 128 + k], Wlin[k * DOUT + o], acc);
    out[t] = acc * inv + blin[o];
}

extern "C" void kernel_launch(void* const* d_in, const int* in_sizes, int n_in,
                              void* d_out, int out_size, void* d_ws, size_t ws_size,
                              hipStream_t stream) {
    const float* x    = (const float*)d_in[0];
    const int*   ei   = (const int*)d_in[1];
    const int*   batch= (const int*)d_in[2];
    const float* W1   = (const float*)d_in[3];
    const float* b1   = (const float*)d_in[4];
    const float* W2   = (const float*)d_in[5];
    const float* b2   = (const float*)d_in[6];
    const float* Wlin = (const float*)d_in[7];
    const float* blin = (const float*)d_in[8];
    float* out = (float*)d_out;

    const int N = in_sizes[2];          // 50000
    const int E = in_sizes[1] / 2;      // 800000
    const int DIN = in_sizes[0] / N;    // 128

    // workspace carve-up (256B aligned)
    char* base = (char*)d_ws;
    size_t off = 0;
    auto alloc = [&](size_t bytes) {
        char* p = base + off;
        off = (off + bytes + 255) & ~(size_t)255;
        return p;
    };
    int*   deg    = (int*)  alloc((size_t)N * 4);
    int*   rowptr = (int*)  alloc((size_t)(N + 1) * 4);
    int*   cursor = (int*)  alloc((size_t)N * 4);
    float* dinv   = (float*)alloc((size_t)N * 4);
    int2*  csr    = (int2*) alloc((size_t)E * 8);
    float* h      = (float*)alloc((size_t)N * DH * 4);   // reused for layer-2 pre-agg
    float* x1     = (float*)alloc((size_t)N * DH * 4);
    float* x2     = (float*)alloc((size_t)N * DH * 4);
    float* pool   = (float*)alloc((size_t)NUM_GRAPHS * 128 * 4);
    float* cntf   = (float*)alloc((size_t)NUM_GRAPHS * 4);
    (void)ws_size; (void)n_in; (void)out_size; (void)DIN;

    hipMemsetAsync(deg, 0, (size_t)N * 4, stream);
    hipMemsetAsync(pool, 0, (size_t)NUM_GRAPHS * 128 * 4, stream);
    hipMemsetAsync(cntf, 0, (size_t)NUM_GRAPHS * 4, stream);

    // CSR build (shared by both conv layers)
    count_kernel<<<(E + 255) / 256, 256, 0, stream>>>(ei, deg, E);
    scan_kernel<<<1, 1024, 0, stream>>>(deg, rowptr, cursor, dinv, N);
    fill_kernel<<<(E + 255) / 256, 256, 0, stream>>>(ei, cursor, dinv, csr, E);

    // layer 1: waves = ceil(N/4), 4 waves per block
    int waves1 = (N + 3) / 4;
    gemm_kernel<128><<<(waves1 + 3) / 4, 256, 0, stream>>>(x, W1, h, N);
    agg_kernel<<<(N + 3) / 4, 256, 0, stream>>>(h, csr, rowptr, dinv, b1, x1, N);
    // layer 2 (h buffer reused)
    gemm_kernel<64><<<(waves1 + 3) / 4, 256, 0, stream>>>(x1, W2, h, N);
    agg_kernel<<<(N + 3) / 4, 256, 0, stream>>>(h, csr, rowptr, dinv, b2, x2, N);

    // pooling + head
    const int nodesPerBlock = 32;
    pool_kernel<<<(N + nodesPerBlock - 1) / nodesPerBlock, 128, 0, stream>>>(
        x1, x2, batch, pool, cntf, N, nodesPerBlock);
    final_kernel<<<1, 512, 0, stream>>>(pool, cntf, Wlin, blin, out);
}

// Round 5
// 372.063 us; speedup vs baseline: 2.0385x; 1.3491x over previous
//
#include <hip/hip_runtime.h>

static constexpr int NUM_GRAPHS = 64;
static constexpr int DH = 64;      // hidden dim == wave size
static constexpr int DOUT = 7;

// ---------- CSR build ----------
__global__ void count_kernel(const int* __restrict__ ei, int* __restrict__ deg, int E) {
    int e = blockIdx.x * blockDim.x + threadIdx.x;
    if (e < E) atomicAdd(&deg[ei[E + e]], 1);   // dst row of edge_index
}

// per-block degree sums
__global__ __launch_bounds__(256) void partial_kernel(const int* __restrict__ deg,
                                                      int* __restrict__ bsum, int N) {
    __shared__ int sh[256];
    int t = threadIdx.x;
    int i = blockIdx.x * 256 + t;
    sh[t] = (i < N) ? deg[i] : 0;
    __syncthreads();
    for (int s = 128; s > 0; s >>= 1) {
        if (t < s) sh[t] += sh[t + s];
        __syncthreads();
    }
    if (t == 0) bsum[blockIdx.x] = sh[0];
}

// per-block: offset = sum(bsum[0..b)), then 256-wide LDS scan of this chunk
__global__ __launch_bounds__(256) void emit_kernel(const int* __restrict__ deg,
                                                   const int* __restrict__ bsum,
                                                   int* __restrict__ rowptr,
                                                   int* __restrict__ cursor,
                                                   float* __restrict__ dinv, int N) {
    __shared__ int red[256];
    __shared__ int sh[256];
    int t = threadIdx.x;
    int b = blockIdx.x;
    int i = b * 256 + t;

    // cooperative sum of preceding block sums
    int part = 0;
    for (int j = t; j < b; j += 256) part += bsum[j];
    red[t] = part;
    __syncthreads();
    for (int s = 128; s > 0; s >>= 1) {
        if (t < s) red[t] += red[t + s];
        __syncthreads();
    }
    int base = red[0];

    // block-local inclusive scan (Hillis-Steele)
    int d = (i < N) ? deg[i] : 0;
    sh[t] = d;
    __syncthreads();
    for (int off = 1; off < 256; off <<= 1) {
        int v = (t >= off) ? sh[t - off] : 0;
        __syncthreads();
        sh[t] += v;
        __syncthreads();
    }
    int excl = sh[t] - d;

    if (i < N) {
        rowptr[i] = base + excl;
        cursor[i] = base + excl;
        dinv[i] = rsqrtf((float)(d + 1));   // +1: self-loop
    }
    if (i == N - 1) rowptr[N] = base + excl + d;
}

__global__ void fill_kernel(const int* __restrict__ ei, int* __restrict__ cursor,
                            const float* __restrict__ dinv, int2* __restrict__ csr, int E) {
    int e = blockIdx.x * blockDim.x + threadIdx.x;
    if (e >= E) return;
    int src = ei[e];
    int dst = ei[E + e];
    int pos = atomicAdd(&cursor[dst], 1);
    float w = dinv[src] * dinv[dst];
    csr[pos] = make_int2(src, __float_as_int(w));
}

// ---------- dense GEMM: h[N,64] = x[N,K] @ W[K,64] ----------
// wave = 4 rows, lane = output column. W stays in L1 (32 KB), loads coalesced
// across lanes and amortized over 4 rows; 16 independent FMA chains.
template <int K>
__global__ __launch_bounds__(256) void gemm_kernel(const float* __restrict__ x,
                                                   const float* __restrict__ W,
                                                   float* __restrict__ h, int N) {
    int c = threadIdx.x & 63;
    int w = blockIdx.x * (blockDim.x >> 6) + (threadIdx.x >> 6);
    int r0 = w * 4;
    if (r0 >= N) return;

    if (r0 + 4 <= N) {
        float acc[4][4] = {};
#pragma unroll 4
        for (int k4 = 0; k4 < K / 4; ++k4) {
            float w0 = W[(4 * k4 + 0) * DH + c];
            float w1 = W[(4 * k4 + 1) * DH + c];
            float w2 = W[(4 * k4 + 2) * DH + c];
            float w3 = W[(4 * k4 + 3) * DH + c];
#pragma unroll
            for (int i = 0; i < 4; ++i) {
                float4 xv = *(const float4*)(x + (size_t)(r0 + i) * K + 4 * k4);
                acc[i][0] = fmaf(xv.x, w0, acc[i][0]);
                acc[i][1] = fmaf(xv.y, w1, acc[i][1]);
                acc[i][2] = fmaf(xv.z, w2, acc[i][2]);
                acc[i][3] = fmaf(xv.w, w3, acc[i][3]);
            }
        }
#pragma unroll
        for (int i = 0; i < 4; ++i)
            h[(size_t)(r0 + i) * DH + c] =
                (acc[i][0] + acc[i][1]) + (acc[i][2] + acc[i][3]);
    } else {
        for (int r = r0; r < N; ++r) {
            float a0 = 0.f, a1 = 0.f, a2 = 0.f, a3 = 0.f;
            for (int k4 = 0; k4 < K / 4; ++k4) {
                float4 xv = *(const float4*)(x + (size_t)r * K + 4 * k4);
                a0 = fmaf(xv.x, W[(4 * k4 + 0) * DH + c], a0);
                a1 = fmaf(xv.y, W[(4 * k4 + 1) * DH + c], a1);
                a2 = fmaf(xv.z, W[(4 * k4 + 2) * DH + c], a2);
                a3 = fmaf(xv.w, W[(4 * k4 + 3) * DH + c], a3);
            }
            h[(size_t)r * DH + c] = (a0 + a1) + (a2 + a3);
        }
    }
}

// ---------- sparse aggregation: one wave per node, lane = channel ----------
// edge loop unrolled x4: 4 independent csr loads + 4 independent row gathers
// in flight per wave -> hides L2/LLC latency.
__global__ __launch_bounds__(256) void agg_kernel(const float* __restrict__ h,
                                                  const int2* __restrict__ csr,
                                                  const int* __restrict__ rowptr,
                                                  const float* __restrict__ dinv,
                                                  const float* __restrict__ bias,
                                                  float* __restrict__ out, int N) {
    int lane = threadIdx.x & 63;
    int node = blockIdx.x * (blockDim.x >> 6) + (threadIdx.x >> 6);
    if (node >= N) return;
    float di = dinv[node];
    float a0 = di * di * h[(size_t)node * DH + lane];   // self-loop term
    float a1 = 0.f, a2 = 0.f, a3 = 0.f;
    int beg = rowptr[node], end = rowptr[node + 1];
    int i = beg;
    for (; i + 4 <= end; i += 4) {
        int2 e0 = csr[i + 0];
        int2 e1 = csr[i + 1];
        int2 e2 = csr[i + 2];
        int2 e3 = csr[i + 3];
        a0 = fmaf(__int_as_float(e0.y), h[(size_t)e0.x * DH + lane], a0);
        a1 = fmaf(__int_as_float(e1.y), h[(size_t)e1.x * DH + lane], a1);
        a2 = fmaf(__int_as_float(e2.y), h[(size_t)e2.x * DH + lane], a2);
        a3 = fmaf(__int_as_float(e3.y), h[(size_t)e3.x * DH + lane], a3);
    }
    for (; i < end; ++i) {
        int2 e = csr[i];
        a0 = fmaf(__int_as_float(e.y), h[(size_t)e.x * DH + lane], a0);
    }
    float acc = (a0 + a1) + (a2 + a3);
    out[(size_t)node * DH + lane] = fmaxf(acc + bias[lane], 0.f);
}

// ---------- mean pool over sorted batch (JK-cat of x1,x2) ----------
__global__ __launch_bounds__(128) void pool_kernel(const float* __restrict__ x1,
                                                   const float* __restrict__ x2,
                                                   const int* __restrict__ batch,
                                                   float* __restrict__ pool,
                                                   float* __restrict__ cntf,
                                                   int N, int nodesPerBlock) {
    int f = threadIdx.x;  // 0..127
    int start = blockIdx.x * nodesPerBlock;
    int end = min(N, start + nodesPerBlock);
    if (start >= end) return;
    int gcur = batch[start];
    float acc = 0.f;
    int c = 0;
    for (int v = start; v < end; ++v) {
        int g = batch[v];               // uniform across block
        if (g != gcur) {
            atomicAdd(&pool[gcur * 128 + f], acc);
            if (f == 0) atomicAdd(&cntf[gcur], (float)c);
            acc = 0.f; c = 0; gcur = g;
        }
        acc += (f < DH) ? x1[(size_t)v * DH + f] : x2[(size_t)v * DH + (f - DH)];
        ++c;
    }
    atomicAdd(&pool[gcur * 128 + f], acc);
    if (f == 0) atomicAdd(&cntf[gcur], (float)c);
}

// ---------- head: (pool/cnt) @ Wlin + blin ----------
__global__ __launch_bounds__(512) void final_kernel(const float* __restrict__ pool,
                                                    const float* __restrict__ cntf,
                                                    const float* __restrict__ Wlin,
                                                    const float* __restrict__ blin,
                                                    float* __restrict__ out) {
    int t = threadIdx.x;
    if (t >= NUM_GRAPHS * DOUT) return;
    int g = t / DOUT, o = t % DOUT;
    float inv = 1.0f / fmaxf(cntf[g], 1.0f);
    float acc = 0.f;
    for (int k = 0; k < 2 * DH; ++k)
        acc = fmaf(pool[g * 128 + k], Wlin[k * DOUT + o], acc);
    out[t] = acc * inv + blin[o];
}

extern "C" void kernel_launch(void* const* d_in, const int* in_sizes, int n_in,
                              void* d_out, int out_size, void* d_ws, size_t ws_size,
                              hipStream_t stream) {
    const float* x    = (const float*)d_in[0];
    const int*   ei   = (const int*)d_in[1];
    const int*   batch= (const int*)d_in[2];
    const float* W1   = (const float*)d_in[3];
    const float* b1   = (const float*)d_in[4];
    const float* W2   = (const float*)d_in[5];
    const float* b2   = (const float*)d_in[6];
    const float* Wlin = (const float*)d_in[7];
    const float* blin = (const float*)d_in[8];
    float* out = (float*)d_out;

    const int N = in_sizes[2];          // 50000
    const int E = in_sizes[1] / 2;      // 800000
    const int DIN = in_sizes[0] / N;    // 128
    const int NB = (N + 255) / 256;     // scan blocks

    // workspace carve-up (256B aligned)
    char* base = (char*)d_ws;
    size_t off = 0;
    auto alloc = [&](size_t bytes) {
        char* p = base + off;
        off = (off + bytes + 255) & ~(size_t)255;
        return p;
    };
    int*   deg    = (int*)  alloc((size_t)N * 4);
    int*   rowptr = (int*)  alloc((size_t)(N + 1) * 4);
    int*   cursor = (int*)  alloc((size_t)N * 4);
    float* dinv   = (float*)alloc((size_t)N * 4);
    int*   bsum   = (int*)  alloc((size_t)NB * 4);
    int2*  csr    = (int2*) alloc((size_t)E * 8);
    float* h      = (float*)alloc((size_t)N * DH * 4);   // reused for layer-2 pre-agg
    float* x1     = (float*)alloc((size_t)N * DH * 4);
    float* x2     = (float*)alloc((size_t)N * DH * 4);
    float* pool   = (float*)alloc((size_t)NUM_GRAPHS * 128 * 4);
    float* cntf   = (float*)alloc((size_t)NUM_GRAPHS * 4);
    (void)ws_size; (void)n_in; (void)out_size; (void)DIN;

    hipMemsetAsync(deg, 0, (size_t)N * 4, stream);
    hipMemsetAsync(pool, 0, (size_t)NUM_GRAPHS * 128 * 4, stream);
    hipMemsetAsync(cntf, 0, (size_t)NUM_GRAPHS * 4, stream);

    // CSR build (shared by both conv layers)
    count_kernel<<<(E + 255) / 256, 256, 0, stream>>>(ei, deg, E);
    partial_kernel<<<NB, 256, 0, stream>>>(deg, bsum, N);
    emit_kernel<<<NB, 256, 0, stream>>>(deg, bsum, rowptr, cursor, dinv, N);
    fill_kernel<<<(E + 255) / 256, 256, 0, stream>>>(ei, cursor, dinv, csr, E);

    // layer 1: waves = ceil(N/4), 4 waves per block
    int waves1 = (N + 3) / 4;
    gemm_kernel<128><<<(waves1 + 3) / 4, 256, 0, stream>>>(x, W1, h, N);
    agg_kernel<<<(N + 3) / 4, 256, 0, stream>>>(h, csr, rowptr, dinv, b1, x1, N);
    // layer 2 (h buffer reused)
    gemm_kernel<64><<<(waves1 + 3) / 4, 256, 0, stream>>>(x1, W2, h, N);
    agg_kernel<<<(N + 3) / 4, 256, 0, stream>>>(h, csr, rowptr, dinv, b2, x2, N);

    // pooling + head
    const int nodesPerBlock = 32;
    pool_kernel<<<(N + nodesPerBlock - 1) / nodesPerBlock, 128, 0, stream>>>(
        x1, x2, batch, pool, cntf, N, nodesPerBlock);
    final_kernel<<<1, 512, 0, stream>>>(pool, cntf, Wlin, blin, out);
}

// Round 6
// 327.907 us; speedup vs baseline: 2.3130x; 1.1347x over previous
//
#include <hip/hip_runtime.h>

static constexpr int NUM_GRAPHS = 64;
static constexpr int DH = 64;      // hidden dim == wave size
static constexpr int DOUT = 7;

// ---------- CSR build ----------
__global__ void count_kernel(const int* __restrict__ ei, int* __restrict__ deg, int E) {
    int e = blockIdx.x * blockDim.x + threadIdx.x;
    if (e < E) atomicAdd(&deg[ei[E + e]], 1);   // dst row of edge_index
}

// per-block degree sums
__global__ __launch_bounds__(256) void partial_kernel(const int* __restrict__ deg,
                                                      int* __restrict__ bsum, int N) {
    __shared__ int sh[256];
    int t = threadIdx.x;
    int i = blockIdx.x * 256 + t;
    sh[t] = (i < N) ? deg[i] : 0;
    __syncthreads();
    for (int s = 128; s > 0; s >>= 1) {
        if (t < s) sh[t] += sh[t + s];
        __syncthreads();
    }
    if (t == 0) bsum[blockIdx.x] = sh[0];
}

// per-block: offset = sum(bsum[0..b)), then 256-wide LDS scan of this chunk
__global__ __launch_bounds__(256) void emit_kernel(const int* __restrict__ deg,
                                                   const int* __restrict__ bsum,
                                                   int* __restrict__ rowptr,
                                                   int* __restrict__ cursor,
                                                   float* __restrict__ dinv, int N) {
    __shared__ int red[256];
    __shared__ int sh[256];
    int t = threadIdx.x;
    int b = blockIdx.x;
    int i = b * 256 + t;

    int part = 0;
    for (int j = t; j < b; j += 256) part += bsum[j];
    red[t] = part;
    __syncthreads();
    for (int s = 128; s > 0; s >>= 1) {
        if (t < s) red[t] += red[t + s];
        __syncthreads();
    }
    int base = red[0];

    int d = (i < N) ? deg[i] : 0;
    sh[t] = d;
    __syncthreads();
    for (int off = 1; off < 256; off <<= 1) {
        int v = (t >= off) ? sh[t - off] : 0;
        __syncthreads();
        sh[t] += v;
        __syncthreads();
    }
    int excl = sh[t] - d;

    if (i < N) {
        rowptr[i] = base + excl;
        cursor[i] = base + excl;
        dinv[i] = rsqrtf((float)(d + 1));   // +1: self-loop
    }
    if (i == N - 1) rowptr[N] = base + excl + d;
}

__global__ void fill_kernel(const int* __restrict__ ei, int* __restrict__ cursor,
                            const float* __restrict__ dinv, int2* __restrict__ csr, int E) {
    int e = blockIdx.x * blockDim.x + threadIdx.x;
    if (e >= E) return;
    int src = ei[e];
    int dst = ei[E + e];
    int pos = atomicAdd(&cursor[dst], 1);
    float w = dinv[src] * dinv[dst];
    csr[pos] = make_int2(src, __float_as_int(w));
}

// ---------- dense GEMM: h[N,64] = x[N,K] @ W[K,64] ----------
// Block = 256 threads = 4 waves, 64 rows/block. W tile + x tile staged in LDS
// (coalesced global loads once per block). Inner loop is LDS-only:
//   W read:  b32, lane c -> bank c%32, 2 lanes/bank = conflict-free
//   x read:  b128 same-address broadcast (conflict-free)
// This removes the uniform-address vector loads that replicated 1024B/instr
// through L1 in the previous version (the measured 72us bottleneck).
template <int K>
__global__ __launch_bounds__(256) void gemm_kernel(const float* __restrict__ x,
                                                   const float* __restrict__ W,
                                                   float* __restrict__ h, int N) {
    __shared__ float4 sX4[64][K / 4];
    __shared__ float  sW[K][64];
    int t = threadIdx.x;
    int r0 = blockIdx.x * 64;

    // stage W [K][64]: K*16 float4s
    const float4* W4 = (const float4*)W;
    for (int v = t; v < K * 16; v += 256) {
        int k = v >> 4, c4 = v & 15;
        *(float4*)&sW[k][c4 * 4] = W4[v];
    }
    // stage x tile [64][K]
    for (int v = t; v < 64 * (K / 4); v += 256) {
        int row = v / (K / 4), c4 = v % (K / 4);
        int gr = min(r0 + row, N - 1);          // clamp tail (stores guarded)
        sX4[row][c4] = *(const float4*)(x + (size_t)gr * K + 4 * c4);
    }
    __syncthreads();

    int c = t & 63;
    int w = t >> 6;           // wave 0..3 -> rows w*16 .. w*16+15
    float acc[16];
#pragma unroll
    for (int r = 0; r < 16; ++r) acc[r] = 0.f;

#pragma unroll 2
    for (int k4 = 0; k4 < K / 4; ++k4) {
        float w0 = sW[4 * k4 + 0][c];
        float w1 = sW[4 * k4 + 1][c];
        float w2 = sW[4 * k4 + 2][c];
        float w3 = sW[4 * k4 + 3][c];
#pragma unroll
        for (int r = 0; r < 16; ++r) {
            float4 xv = sX4[w * 16 + r][k4];    // broadcast
            acc[r] = fmaf(xv.x, w0, acc[r]);
            acc[r] = fmaf(xv.y, w1, acc[r]);
            acc[r] = fmaf(xv.z, w2, acc[r]);
            acc[r] = fmaf(xv.w, w3, acc[r]);
        }
    }

#pragma unroll
    for (int r = 0; r < 16; ++r) {
        int row = r0 + w * 16 + r;
        if (row < N) h[(size_t)row * DH + c] = acc[r];
    }
}

// ---------- sparse aggregation: one wave per node, lane = channel ----------
// edge loop unrolled x8: 8 independent csr loads + row gathers in flight.
__global__ __launch_bounds__(256) void agg_kernel(const float* __restrict__ h,
                                                  const int2* __restrict__ csr,
                                                  const int* __restrict__ rowptr,
                                                  const float* __restrict__ dinv,
                                                  const float* __restrict__ bias,
                                                  float* __restrict__ out, int N) {
    int lane = threadIdx.x & 63;
    int node = blockIdx.x * (blockDim.x >> 6) + (threadIdx.x >> 6);
    if (node >= N) return;
    float di = dinv[node];
    float a0 = di * di * h[(size_t)node * DH + lane];   // self-loop term
    float a1 = 0.f, a2 = 0.f, a3 = 0.f, a4 = 0.f, a5 = 0.f, a6 = 0.f, a7 = 0.f;
    int beg = rowptr[node], end = rowptr[node + 1];
    int i = beg;
    for (; i + 8 <= end; i += 8) {
        int2 e0 = csr[i + 0]; int2 e1 = csr[i + 1];
        int2 e2 = csr[i + 2]; int2 e3 = csr[i + 3];
        int2 e4 = csr[i + 4]; int2 e5 = csr[i + 5];
        int2 e6 = csr[i + 6]; int2 e7 = csr[i + 7];
        a0 = fmaf(__int_as_float(e0.y), h[(size_t)e0.x * DH + lane], a0);
        a1 = fmaf(__int_as_float(e1.y), h[(size_t)e1.x * DH + lane], a1);
        a2 = fmaf(__int_as_float(e2.y), h[(size_t)e2.x * DH + lane], a2);
        a3 = fmaf(__int_as_float(e3.y), h[(size_t)e3.x * DH + lane], a3);
        a4 = fmaf(__int_as_float(e4.y), h[(size_t)e4.x * DH + lane], a4);
        a5 = fmaf(__int_as_float(e5.y), h[(size_t)e5.x * DH + lane], a5);
        a6 = fmaf(__int_as_float(e6.y), h[(size_t)e6.x * DH + lane], a6);
        a7 = fmaf(__int_as_float(e7.y), h[(size_t)e7.x * DH + lane], a7);
    }
    for (; i < end; ++i) {
        int2 e = csr[i];
        a0 = fmaf(__int_as_float(e.y), h[(size_t)e.x * DH + lane], a0);
    }
    float acc = ((a0 + a1) + (a2 + a3)) + ((a4 + a5) + (a6 + a7));
    out[(size_t)node * DH + lane] = fmaxf(acc + bias[lane], 0.f);
}

// ---------- mean pool over sorted batch (JK-cat of x1,x2) ----------
__global__ __launch_bounds__(128) void pool_kernel(const float* __restrict__ x1,
                                                   const float* __restrict__ x2,
                                                   const int* __restrict__ batch,
                                                   float* __restrict__ pool,
                                                   float* __restrict__ cntf,
                                                   int N, int nodesPerBlock) {
    int f = threadIdx.x;  // 0..127
    int start = blockIdx.x * nodesPerBlock;
    int end = min(N, start + nodesPerBlock);
    if (start >= end) return;
    int gcur = batch[start];
    float acc = 0.f;
    int c = 0;
    for (int v = start; v < end; ++v) {
        int g = batch[v];               // uniform across block
        if (g != gcur) {
            atomicAdd(&pool[gcur * 128 + f], acc);
            if (f == 0) atomicAdd(&cntf[gcur], (float)c);
            acc = 0.f; c = 0; gcur = g;
        }
        acc += (f < DH) ? x1[(size_t)v * DH + f] : x2[(size_t)v * DH + (f - DH)];
        ++c;
    }
    atomicAdd(&pool[gcur * 128 + f], acc);
    if (f == 0) atomicAdd(&cntf[gcur], (float)c);
}

// ---------- head: (pool/cnt) @ Wlin + blin ----------
__global__ __launch_bounds__(512) void final_kernel(const float* __restrict__ pool,
                                                    const float* __restrict__ cntf,
                                                    const float* __restrict__ Wlin,
                                                    const float* __restrict__ blin,
                                                    float* __restrict__ out) {
    int t = threadIdx.x;
    if (t >= NUM_GRAPHS * DOUT) return;
    int g = t / DOUT, o = t % DOUT;
    float inv = 1.0f / fmaxf(cntf[g], 1.0f);
    float acc = 0.f;
    for (int k = 0; k < 2 * DH; ++k)
        acc = fmaf(pool[g * 128 + k], Wlin[k * DOUT + o], acc);
    out[t] = acc * inv + blin[o];
}

extern "C" void kernel_launch(void* const* d_in, const int* in_sizes, int n_in,
                              void* d_out, int out_size, void* d_ws, size_t ws_size,
                              hipStream_t stream) {
    const float* x    = (const float*)d_in[0];
    const int*   ei   = (const int*)d_in[1];
    const int*   batch= (const int*)d_in[2];
    const float* W1   = (const float*)d_in[3];
    const float* b1   = (const float*)d_in[4];
    const float* W2   = (const float*)d_in[5];
    const float* b2   = (const float*)d_in[6];
    const float* Wlin = (const float*)d_in[7];
    const float* blin = (const float*)d_in[8];
    float* out = (float*)d_out;

    const int N = in_sizes[2];          // 50000
    const int E = in_sizes[1] / 2;      // 800000
    const int DIN = in_sizes[0] / N;    // 128
    const int NB = (N + 255) / 256;     // scan blocks

    // workspace carve-up (256B aligned)
    char* base = (char*)d_ws;
    size_t off = 0;
    auto alloc = [&](size_t bytes) {
        char* p = base + off;
        off = (off + bytes + 255) & ~(size_t)255;
        return p;
    };
    int*   deg    = (int*)  alloc((size_t)N * 4);
    int*   rowptr = (int*)  alloc((size_t)(N + 1) * 4);
    int*   cursor = (int*)  alloc((size_t)N * 4);
    float* dinv   = (float*)alloc((size_t)N * 4);
    int*   bsum   = (int*)  alloc((size_t)NB * 4);
    int2*  csr    = (int2*) alloc((size_t)E * 8);
    float* h      = (float*)alloc((size_t)N * DH * 4);   // reused for layer-2 pre-agg
    float* x1     = (float*)alloc((size_t)N * DH * 4);
    float* x2     = (float*)alloc((size_t)N * DH * 4);
    float* pool   = (float*)alloc((size_t)NUM_GRAPHS * 128 * 4);
    float* cntf   = (float*)alloc((size_t)NUM_GRAPHS * 4);
    (void)ws_size; (void)n_in; (void)out_size; (void)DIN;

    hipMemsetAsync(deg, 0, (size_t)N * 4, stream);
    hipMemsetAsync(pool, 0, (size_t)NUM_GRAPHS * 128 * 4, stream);
    hipMemsetAsync(cntf, 0, (size_t)NUM_GRAPHS * 4, stream);

    // CSR build (shared by both conv layers)
    count_kernel<<<(E + 255) / 256, 256, 0, stream>>>(ei, deg, E);
    partial_kernel<<<NB, 256, 0, stream>>>(deg, bsum, N);
    emit_kernel<<<NB, 256, 0, stream>>>(deg, bsum, rowptr, cursor, dinv, N);
    fill_kernel<<<(E + 255) / 256, 256, 0, stream>>>(ei, cursor, dinv, csr, E);

    // layer 1: 64 rows per block
    gemm_kernel<128><<<(N + 63) / 64, 256, 0, stream>>>(x, W1, h, N);
    agg_kernel<<<(N + 3) / 4, 256, 0, stream>>>(h, csr, rowptr, dinv, b1, x1, N);
    // layer 2 (h buffer reused)
    gemm_kernel<64><<<(N + 63) / 64, 256, 0, stream>>>(x1, W2, h, N);
    agg_kernel<<<(N + 3) / 4, 256, 0, stream>>>(h, csr, rowptr, dinv, b2, x2, N);

    // pooling + head
    const int nodesPerBlock = 32;
    pool_kernel<<<(N + nodesPerBlock - 1) / nodesPerBlock, 128, 0, stream>>>(
        x1, x2, batch, pool, cntf, N, nodesPerBlock);
    final_kernel<<<1, 512, 0, stream>>>(pool, cntf, Wlin, blin, out);
}